// Round 6
// baseline (436.571 us; speedup 1.0000x reference)
//
#include <hip/hip_runtime.h>
#include <hip/hip_bf16.h>
#include <stdint.h>

#define DIM   1024
#define NSEQ  4096
#define NBAT  4
#define NH    16
#define HD    64
#define MROWS (NBAT*NSEQ)   // 16384

typedef __attribute__((ext_vector_type(8))) short  short8;
typedef __attribute__((ext_vector_type(4))) float  f32x4;
typedef __attribute__((ext_vector_type(4))) unsigned int  u32x4;
typedef __attribute__((ext_vector_type(4))) unsigned short u16x4;

// ---- helpers -------------------------------------------------------------
__device__ inline unsigned short bf16_rne(float x) {
    unsigned u = __builtin_bit_cast(unsigned, x);
    u += 0x7FFFu + ((u >> 16) & 1u);
    return (unsigned short)(u >> 16);
}
__device__ inline float bf16_to_f32(unsigned short h) {
    return __builtin_bit_cast(float, ((unsigned)h) << 16);
}
__device__ inline void gld16(const unsigned short* g, unsigned short* l) {
    __builtin_amdgcn_global_load_lds(
        (const __attribute__((address_space(1))) unsigned int*)g,
        (__attribute__((address_space(3))) unsigned int*)l,
        16, 0, 0);
}

// ---- all 4 weights fp32->bf16, one launch --------------------------------
__global__ __launch_bounds__(256) void wcvt_kernel(const float* __restrict__ s0, const float* __restrict__ s1,
                                                   const float* __restrict__ s2, const float* __restrict__ s3,
                                                   unsigned short* __restrict__ d0, unsigned short* __restrict__ d1,
                                                   unsigned short* __restrict__ d2, unsigned short* __restrict__ d3) {
    int i = blockIdx.x * 256 + threadIdx.x;     // 0..1048575, 4 f32 each
    int w = i >> 18, j = i & 262143;
    const float* s = (w == 0) ? s0 : (w == 1) ? s1 : (w == 2) ? s2 : s3;
    unsigned short* d = (w == 0) ? d0 : (w == 1) ? d1 : (w == 2) ? d2 : d3;
    f32x4 v = ((const f32x4*)s)[j];
    u16x4 o;
    o[0] = bf16_rne(v[0]); o[1] = bf16_rne(v[1]);
    o[2] = bf16_rne(v[2]); o[3] = bf16_rne(v[3]);
    ((u16x4*)d)[j] = o;
}

// ---- activation fp32->bf16 converters ------------------------------------
__global__ __launch_bounds__(256) void acvt2_kernel(const float* __restrict__ s0, const float* __restrict__ s1,
                                                    unsigned short* __restrict__ d0, unsigned short* __restrict__ d1) {
    int i = blockIdx.x * 256 + threadIdx.x;     // 0..8388607 (2 tensors x 4M f32x4)
    int w = i >> 22, j = i & 4194303;
    const float* s = w ? s1 : s0;
    unsigned short* d = w ? d1 : d0;
    f32x4 v = ((const f32x4*)s)[j];
    u16x4 o;
    o[0] = bf16_rne(v[0]); o[1] = bf16_rne(v[1]);
    o[2] = bf16_rne(v[2]); o[3] = bf16_rne(v[3]);
    ((u16x4*)d)[j] = o;
}
__global__ __launch_bounds__(256) void acvt1_kernel(const float* __restrict__ s0, unsigned short* __restrict__ d0) {
    int i = blockIdx.x * 256 + threadIdx.x;     // 0..4194303
    f32x4 v = ((const f32x4*)s0)[i];
    u16x4 o;
    o[0] = bf16_rne(v[0]); o[1] = bf16_rne(v[1]);
    o[2] = bf16_rne(v[2]); o[3] = bf16_rne(v[3]);
    ((u16x4*)d0)[i] = o;
}

// ---- deep-pipelined 256x256 GEMM: C = act(A_bf16 @ W_bf16^T + bias) ------
// 8 waves (2M x 4N), BK=32, ring-of-4 LDS K-tile buffers (128 KiB total),
// depth-3 prefetch via global_load_lds, counted s_waitcnt vmcnt(8) (never 0
// in-loop), XOR-swizzled LDS (conflict-free ds_read_b128), setprio around
// MFMA clusters, bijective XCD blockIdx swizzle.
//
// LDS swizzle (super-row layout, BK=32 -> 64B logical rows):
//   phys_byte(row,col) = (row>>1)*128 + (row&1)*64
//                      + ((col>>3) ^ ((row>>1)&3))*16 + (col&7)*2
// Involution check vs linear global_load_lds dest (slot byte = t*16):
//   srow=2*(t>>3)+((t>>2)&1), scol=8*((t&3)^((t>>3)&3))
//   phys(srow,scol) = (t>>3)*128 + t[2]*64 + (t&3)*16 = t*16  -> exact.
// Read: lanes 0-15 of quad q hit bank-groups 4*(q^(p&3))+16*(lm&1), p=lm>>1:
// 8 distinct 4-bank groups x 2 lanes = minimum 2-way = free (m136).
template<int ACT, int OUTF32>
__global__ __launch_bounds__(512, 2) void gemm8_kernel(const unsigned short* __restrict__ Ab,
                                                       const unsigned short* __restrict__ Wb,
                                                       const float* __restrict__ bias,
                                                       void* __restrict__ Cp,
                                                       const int* __restrict__ mask) {
    __shared__ __align__(16) char smem[131072];   // A slots [0,64K), B slots [64K,128K)

    // bijective XCD swizzle: nwg=256, 32 consecutive (mtile-major) blocks/XCD
    const int bid = blockIdx.x;
    const int swz = (bid & 7) * 32 + (bid >> 3);
    const int tm  = (swz >> 2) * 256;
    const int tn  = (swz & 3) * 256;

    const int t    = threadIdx.x;
    const int w    = t >> 6;
    const int lane = t & 63;
    const int wm   = w >> 2;          // 0..1  (A-half, 128 rows)
    const int wn   = w & 3;           // 0..3  (64-col strip)
    const int lm   = lane & 15;
    const int quad = lane >> 4;

    // fragment-read base byte offsets (within a 16 KiB slot)
    const int xr    = ((quad ^ ((lm >> 1) & 3)) << 4) + (lm & 1) * 64;
    const int abase = (wm * 64 + (lm >> 1)) * 128 + xr;
    const int bbase = (wn * 32 + (lm >> 1)) * 128 + xr;

    // staging source (inverse-swizzled global address, rule #21)
    const int srow = ((t >> 3) << 1) + ((t >> 2) & 1);       // 0..127
    const int scol = ((t & 3) ^ ((t >> 3) & 3)) * 8;
    const unsigned short* pa = Ab + (size_t)(tm + srow) * DIM + scol;
    const unsigned short* pb = Wb + (size_t)(tn + srow) * DIM + scol;

    f32x4 acc[8][4] = {};
    const int NT = DIM / 32;          // 32 K-tiles

    // prologue: stage tiles 0,1,2 (12 gld16; batch order pinned so vmcnt(8)
    // retires exactly the tile-0 batch)
#pragma unroll
    for (int pt = 0; pt < 3; ++pt) {
        char* dst = smem + pt * 16384;
        gld16(pa + pt * 32,             (unsigned short*)(dst + t * 16));
        gld16(pa + 128 * DIM + pt * 32, (unsigned short*)(dst + 8192 + t * 16));
        gld16(pb + pt * 32,             (unsigned short*)(dst + 65536 + t * 16));
        gld16(pb + 128 * DIM + pt * 32, (unsigned short*)(dst + 65536 + 8192 + t * 16));
        __builtin_amdgcn_sched_barrier(0);   // pin batch boundaries
    }
    asm volatile("s_waitcnt vmcnt(8)" ::: "memory");   // tile 0 landed (all waves: + barrier)
    __builtin_amdgcn_s_barrier();
    __builtin_amdgcn_sched_barrier(0);

    short8 bf[4];
    for (int kt = 0; kt < NT; ++kt) {
        const int  slot = (kt & 3) * 16384;
        const int  ks   = (kt + 3 < NT) ? kt + 3 : NT - 1;  // tail: redundant re-stage keeps vmcnt counts uniform
        char*      stg  = smem + ((kt + 3) & 3) * 16384;    // occupant (tile kt-1) fully read before iter kt began

        // ---- phase A: stage A-halves of tile kt+3; compute i=0..3 --------
        gld16(pa + ks * 32,             (unsigned short*)(stg + t * 16));
        gld16(pa + 128 * DIM + ks * 32, (unsigned short*)(stg + 8192 + t * 16));
        short8 af[4];
#pragma unroll
        for (int i = 0; i < 4; ++i)
            af[i] = *(const short8*)(smem + slot + abase + i * 1024);
#pragma unroll
        for (int j = 0; j < 4; ++j)
            bf[j] = *(const short8*)(smem + slot + 65536 + bbase + j * 1024);
        __builtin_amdgcn_s_barrier();
        asm volatile("s_waitcnt lgkmcnt(0)" ::: "memory");
        __builtin_amdgcn_sched_barrier(0);
        __builtin_amdgcn_s_setprio(1);
#pragma unroll
        for (int i = 0; i < 4; ++i)
#pragma unroll
            for (int j = 0; j < 4; ++j)
                acc[i][j] = __builtin_amdgcn_mfma_f32_16x16x32_bf16(af[i], bf[j], acc[i][j], 0, 0, 0);
        __builtin_amdgcn_s_setprio(0);
        __builtin_amdgcn_s_barrier();
        __builtin_amdgcn_sched_barrier(0);

        // ---- phase B: stage B-halves of tile kt+3; compute i=4..7 --------
        gld16(pb + ks * 32,             (unsigned short*)(stg + 65536 + t * 16));
        gld16(pb + 128 * DIM + ks * 32, (unsigned short*)(stg + 65536 + 8192 + t * 16));
#pragma unroll
        for (int i = 0; i < 4; ++i)
            af[i] = *(const short8*)(smem + slot + abase + 4096 + i * 1024);
        __builtin_amdgcn_s_barrier();
        asm volatile("s_waitcnt lgkmcnt(0)" ::: "memory");
        __builtin_amdgcn_sched_barrier(0);
        __builtin_amdgcn_s_setprio(1);
#pragma unroll
        for (int i = 0; i < 4; ++i)
#pragma unroll
            for (int j = 0; j < 4; ++j)
                acc[i + 4][j] = __builtin_amdgcn_mfma_f32_16x16x32_bf16(af[i], bf[j], acc[i + 4][j], 0, 0, 0);
        __builtin_amdgcn_s_setprio(0);
        // counted drain: tiles kt+2, kt+3 (8 loads) stay in flight; tile kt+1 landed
        asm volatile("s_waitcnt vmcnt(8)" ::: "memory");
        __builtin_amdgcn_s_barrier();
        __builtin_amdgcn_sched_barrier(0);
    }

    // drain tail re-stages: no LDS-writes may be in flight at block retire
    // (successor block on this CU inherits the LDS region)
    asm volatile("s_waitcnt vmcnt(0)" ::: "memory");

    // ---- epilogue ---------------------------------------------------------
    const int crow0 = tm + wm * 128 + quad * 4;
    const int ccol0 = tn + wn * 64 + lm;
#pragma unroll
    for (int i = 0; i < 8; ++i) {
#pragma unroll
        for (int r = 0; r < 4; ++r) {
            const int row = crow0 + i * 16 + r;
            int mz = 0;
            if constexpr (ACT == 2) mz = mask[row];
#pragma unroll
            for (int j = 0; j < 4; ++j) {
                const int col = ccol0 + j * 16;
                float v = acc[i][j][r] + bias[col];
                if constexpr (ACT >= 1) v = v > 0.f ? v : 0.f;
                if constexpr (ACT == 2) { if (mz) v = 0.f; }
                if constexpr (OUTF32)
                    ((float*)Cp)[(size_t)row * DIM + col] = v;
                else
                    ((unsigned short*)Cp)[(size_t)row * DIM + col] = bf16_rne(v);
            }
        }
    }
}

// ---- kv via MFMA: per (bh, chunk) compute partial kvT[e][d] over 512 rows -
__device__ inline int rowoff(int d) { return d * 40 + ((d >> 3) & 1) * 8; }

__global__ __launch_bounds__(256) void kvmfma_kernel(const unsigned short* __restrict__ kb,
                                                     const unsigned short* __restrict__ vb,
                                                     float* __restrict__ kvT8,
                                                     float* __restrict__ ksum8) {
    __shared__ unsigned short kT[2624];
    __shared__ unsigned short vT[2624];
    __shared__ float ksl[64];

    const int bh    = blockIdx.x;            // 0..63
    const int bb    = bh >> 4, h = bh & 15;
    const int chunk = blockIdx.y;            // 0..7, 512 rows each
    const int t     = threadIdx.x;
    const int w     = t >> 6;
    const int lane  = t & 63;
    const int lm    = lane & 15;
    const int quad  = lane >> 4;
    const int sn    = t >> 3;                // staging row 0..31
    const int d0    = (t & 7) * 8;           // staging d offset

    const size_t gbase = ((size_t)bb * NSEQ + (size_t)chunk * 512) * DIM + h * HD;
    const unsigned short* kp = kb + gbase + (size_t)sn * DIM + d0;
    const unsigned short* vp = vb + gbase + (size_t)sn * DIM + d0;

    if (t < 64) ksl[t] = 0.f;

    float ks[8] = {};
    f32x4 acc[4] = {};

    for (int n0 = 0; n0 < 512; n0 += 32) {
        short8 kx = *(const short8*)(kp + (size_t)n0 * DIM);
        short8 vx = *(const short8*)(vp + (size_t)n0 * DIM);
        __syncthreads();
#pragma unroll
        for (int j = 0; j < 8; ++j) {
            const int ro = rowoff(d0 + j);
            kT[ro + sn] = (unsigned short)kx[j];
            vT[ro + sn] = (unsigned short)vx[j];
            ks[j] += bf16_to_f32((unsigned short)kx[j]);
        }
        __syncthreads();
        short8 afrag = *(const short8*)(vT + rowoff(w * 16 + lm) + quad * 8);
#pragma unroll
        for (int jd = 0; jd < 4; ++jd) {
            short8 bfrag = *(const short8*)(kT + rowoff(jd * 16 + lm) + quad * 8);
            acc[jd] = __builtin_amdgcn_mfma_f32_16x16x32_bf16(afrag, bfrag, acc[jd], 0, 0, 0);
        }
    }

    const size_t obase = ((size_t)chunk * 64 + bh) * 4096;
#pragma unroll
    for (int jd = 0; jd < 4; ++jd)
#pragma unroll
        for (int r = 0; r < 4; ++r) {
            const int e = w * 16 + quad * 4 + r;
            const int d = jd * 16 + lm;
            kvT8[obase + e * 64 + d] = acc[jd][r];
        }

    __syncthreads();
#pragma unroll
    for (int j = 0; j < 8; ++j) atomicAdd(&ksl[d0 + j], ks[j]);
    __syncthreads();
    if (t < 64) ksum8[((size_t)chunk * 64 + bh) * 64 + t] = ksl[t];
}

// ---- reduce 8 chunk-slices -> kvTb bf16 + ksum fp32 ----------------------
__global__ __launch_bounds__(256) void kvsum_kernel(const float* __restrict__ kvT8,
                                                    const float* __restrict__ ksum8,
                                                    unsigned short* __restrict__ kvTb,
                                                    float* __restrict__ ksum) {
    int idx = blockIdx.x * 256 + threadIdx.x;
    if (idx < 262144) {
        float s = 0.f;
#pragma unroll
        for (int c = 0; c < 8; ++c) s += kvT8[(size_t)c * 262144 + idx];
        kvTb[idx] = bf16_rne(s);
    } else {
        int j = idx - 262144;   // < 4096
        float s = 0.f;
#pragma unroll
        for (int c = 0; c < 8; ++c) s += ksum8[(size_t)c * 4096 + j];
        ksum[j] = s;
    }
}

// ---- attention apply + fused denominator ---------------------------------
__global__ __launch_bounds__(256) void attnout_kernel(const unsigned short* __restrict__ qb,
                                                      const unsigned short* __restrict__ kvTb,
                                                      const float* __restrict__ ksum,
                                                      unsigned short* __restrict__ attn) {
    const int n0   = blockIdx.x * 16;
    const int bb   = n0 >> 12;
    const int t    = threadIdx.x;
    const int w    = t >> 6;
    const int lane = t & 63;
    const int lm   = lane & 15;
    const int quad = lane >> 4;

    for (int hh = 0; hh < 4; ++hh) {
        const int h  = w * 4 + hh;
        const int bh = bb * NH + h;
        const unsigned short* qp = qb + (size_t)(n0 + lm) * DIM + h * HD + quad * 8;
        short8 a0 = *(const short8*)qp;
        short8 a1 = *(const short8*)(qp + 32);

        const float* ksp = ksum + (size_t)bh * HD + quad * 8;
        float part = 0.f;
#pragma unroll
        for (int j = 0; j < 8; ++j)
            part += bf16_to_f32((unsigned short)a0[j]) * ksp[j]
                  + bf16_to_f32((unsigned short)a1[j]) * ksp[32 + j];
        part += __shfl_xor(part, 16, 64);
        part += __shfl_xor(part, 32, 64);
        float dinv = 1.f / (part + 1e-6f);

        f32x4 accs[4];
#pragma unroll
        for (int j = 0; j < 4; ++j) {
            const unsigned short* bp = kvTb + ((size_t)bh * HD + j * 16 + lm) * HD + quad * 8;
            short8 b0 = *(const short8*)bp;
            short8 b1 = *(const short8*)(bp + 32);
            f32x4 c = {};
            c = __builtin_amdgcn_mfma_f32_16x16x32_bf16(a0, b0, c, 0, 0, 0);
            c = __builtin_amdgcn_mfma_f32_16x16x32_bf16(a1, b1, c, 0, 0, 0);
            accs[j] = c;
        }
        float dv[4];
#pragma unroll
        for (int r = 0; r < 4; ++r)
            dv[r] = __shfl(dinv, quad * 4 + r, 64);
#pragma unroll
        for (int j = 0; j < 4; ++j)
#pragma unroll
            for (int r = 0; r < 4; ++r) {
                const int row = n0 + quad * 4 + r;
                attn[(size_t)row * DIM + h * HD + j * 16 + lm] = bf16_rne(accs[j][r] * dv[r]);
            }
    }
}

// ---- host ----------------------------------------------------------------
extern "C" void kernel_launch(void* const* d_in, const int* in_sizes, int n_in,
                              void* d_out, int out_size, void* d_ws, size_t ws_size,
                              hipStream_t stream) {
    const float* query = (const float*)d_in[0];
    const float* key   = (const float*)d_in[1];
    const float* value = (const float*)d_in[2];
    const float* Wq    = (const float*)d_in[3];
    const float* bq    = (const float*)d_in[4];
    const float* Wk    = (const float*)d_in[5];
    const float* bk    = (const float*)d_in[6];
    const float* Wv    = (const float*)d_in[7];
    const float* bv    = (const float*)d_in[8];
    const float* Wo    = (const float*)d_in[9];
    const float* bo    = (const float*)d_in[10];
    const int*   mask  = (const int*)d_in[11];
    float* out = (float*)d_out;
    char*  ws  = (char*)d_ws;
    const size_t MB = 1024ull * 1024ull;

    // ws layout (74 MB, unchanged from verified baseline):
    unsigned short* Wqb  = (unsigned short*)(ws + 0 * MB);
    unsigned short* Wkb  = (unsigned short*)(ws + 2 * MB);
    unsigned short* Wvb  = (unsigned short*)(ws + 4 * MB);
    unsigned short* Wob  = (unsigned short*)(ws + 6 * MB);
    unsigned short* qb   = (unsigned short*)(ws + 8 * MB);    // 32 MB
    unsigned short* kb   = (unsigned short*)(ws + 40 * MB);   // 32 MB (reused as attn)
    unsigned short* kvTb = (unsigned short*)(ws + 72 * MB);   // 0.5 MB
    float*          ksum = (float*)(ws + 73 * MB);            // 16 KB
    unsigned short* attn = kb;

    // d_out (64 MB) as scratch until final GEMM (lifetimes verified):
    //   Qbf: d_out[0:32)   live acvt2 -> gemmQ
    //   Kbf: d_out[32:64)  live acvt2 -> gemmK
    //   Vbf: d_out[32:64)  live acvt1 -> gemmV   (Kbf dead, acvt1 runs after gemmK)
    //   vb : d_out[0:32)   live gemmV -> kvmfma  (Qbf dead)
    //   kvT8/ksum8: d_out[32:40.125) live kvmfma -> kvsum (Vbf dead)
    unsigned short* Qbf   = (unsigned short*)d_out;
    unsigned short* Kbf   = (unsigned short*)((char*)d_out + 32 * MB);
    unsigned short* Vbf   = Kbf;
    unsigned short* vb    = (unsigned short*)d_out;
    float*          kvT8  = (float*)((char*)d_out + 32 * MB);
    float*          ksum8 = (float*)((char*)d_out + 40 * MB);

    wcvt_kernel<<<4096, 256, 0, stream>>>(Wq, Wk, Wv, Wo, Wqb, Wkb, Wvb, Wob);
    acvt2_kernel<<<32768, 256, 0, stream>>>(query, key, Qbf, Kbf);

    gemm8_kernel<1, 0><<<256, 512, 0, stream>>>(Qbf, Wqb, bq, qb, nullptr);
    gemm8_kernel<2, 0><<<256, 512, 0, stream>>>(Kbf, Wkb, bk, kb, mask);
    acvt1_kernel<<<16384, 256, 0, stream>>>(value, Vbf);
    gemm8_kernel<0, 0><<<256, 512, 0, stream>>>(Vbf, Wvb, bv, vb, nullptr);

    kvmfma_kernel<<<dim3(64, 8), 256, 0, stream>>>(kb, vb, kvT8, ksum8);
    kvsum_kernel<<<1040, 256, 0, stream>>>(kvT8, ksum8, kvTb, ksum);
    attnout_kernel<<<1024, 256, 0, stream>>>(qb, kvTb, ksum, attn);

    gemm8_kernel<0, 1><<<256, 512, 0, stream>>>(attn, Wob, bo, out, nullptr);
}